// Round 1
// baseline (360.188 us; speedup 1.0000x reference)
//
#include <hip/hip_runtime.h>
#include <stdint.h>

// Problem constants: B=64, T=32, J=128, N=64, IN_F=4096, OUT_F=256
#define Bv   64
#define Tv   32
#define Jv   128
#define Nv   64
#define Lv   256
#define INFv 4096

typedef __attribute__((ext_vector_type(8))) short  short8;   // 8 bf16 (4 VGPRs) — MFMA A/B frag
typedef __attribute__((ext_vector_type(4))) float  floatx4;  // MFMA C/D frag

// f32 -> bf16 bits, round-to-nearest-even (inputs are finite normals)
__device__ __forceinline__ unsigned int f2bf(float f) {
  union { float f; unsigned int u; } v; v.f = f;
  unsigned int r = v.u + 0x7fffu + ((v.u >> 16) & 1u);
  return r >> 16;
}

// Kernel A (unchanged): transpose+convert full_weight [256][4096] f32 -> Wt [4096][256] bf16.
__global__ __launch_bounds__(256) void wt_transpose_kernel(
    const float* __restrict__ w, unsigned short* __restrict__ wt) {
  int i_base = blockIdx.x * 16;      // 256 blocks x 16 i-values
  int wave = threadIdx.x >> 6;
  int lane = threadIdx.x & 63;
  #pragma unroll
  for (int r = 0; r < 4; ++r) {
    int i = i_base + wave * 4 + r;
    unsigned int b0 = f2bf(w[(size_t)(4 * lane + 0) * INFv + i]);
    unsigned int b1 = f2bf(w[(size_t)(4 * lane + 1) * INFv + i]);
    unsigned int b2 = f2bf(w[(size_t)(4 * lane + 2) * INFv + i]);
    unsigned int b3 = f2bf(w[(size_t)(4 * lane + 3) * INFv + i]);
    uint2 u;
    u.x = b0 | (b1 << 16);
    u.y = b2 | (b3 << 16);
    *(uint2*)(wt + (size_t)i * Lv + 4 * lane) = u;
  }
}

// Main kernel v2: NO LDS, NO barriers. One block per (b,t, j-half); 4 waves split l.
// Swapped MFMA roles: A = G[l][n] (gathered wt rows, register-direct), B = X[j][n].
// C/D layout (verified): col=lane&15 -> j, row=qd*4+r -> l  => per-lane acc quad is
// 4 CONSECUTIVE l values -> float4 nontemporal stores.
template <int USE_WT>
__global__ __launch_bounds__(256, 3) void masklin_kernel(
    const float* __restrict__ x, const int* __restrict__ idx,
    const unsigned short* __restrict__ wt, const float* __restrict__ wfull,
    float* __restrict__ y) {
  const int blk  = blockIdx.x;       // 0..4095
  const int bt   = blk >> 1;         // (b,t)
  const int jh   = blk & 1;          // j-half: rows [64*jh, 64*jh+64)
  const int b    = bt >> 5;
  const int t    = bt & 31;
  const int tid  = threadIdx.x;
  const int wave = tid >> 6;
  const int lane = tid & 63;
  const int m    = lane & 15;        // 16-row/col index within MFMA tile
  const int qd   = lane >> 4;        // quad index (k-chunk / row-quad)
  const int lbase = wave << 6;       // wave's l-range [lbase, lbase+64)
  const int jbase = jh << 6;

  // ---- indices this lane needs: n = ks*32 + qd*8 + j  (16 values) ----
  // idx layout [b][n][t] int32 (harness convention, verified by prior passing kernel)
  const int* idxp = idx + ((b << 6) * Tv) + t;
  int rows[16];
  #pragma unroll
  for (int ks = 0; ks < 2; ++ks)
    #pragma unroll
    for (int j = 0; j < 8; ++j)
      rows[ks * 8 + j] = idxp[((ks << 5) + (qd << 3) + j) * Tv];

  // ---- A fragments: afr[ks][lt], element j = G[l][n] = wt[idx[n]][l] ----
  // Per instruction: 4 qd-rows x 32B contiguous (16 lanes x 2B) — L2-resident table.
  short8 afr[2][4];
  #pragma unroll
  for (int ks = 0; ks < 2; ++ks) {
    #pragma unroll
    for (int lt = 0; lt < 4; ++lt) {
      const int lcol = lbase + (lt << 4) + m;
      unsigned int e[8];
      #pragma unroll
      for (int j = 0; j < 8; ++j) {
        if (USE_WT) {
          e[j] = wt[(unsigned int)rows[ks * 8 + j] * Lv + lcol];
        } else {
          e[j] = f2bf(wfull[(size_t)lcol * INFv + rows[ks * 8 + j]]);  // fallback, slow
        }
      }
      uint4 v;
      v.x = e[0] | (e[1] << 16);
      v.y = e[2] | (e[3] << 16);
      v.z = e[4] | (e[5] << 16);
      v.w = e[6] | (e[7] << 16);
      afr[ks][lt] = *(short8*)&v;
    }
  }

  // ---- B fragments from X: bfr[ks][jt], element = x[bt][j = jbase+jt*16+m][k] ----
  // 8 consecutive f32 per lane (32B, aligned); 16 rows x 128B segments per instr.
  // All 4 waves read the same 8KB half-tile -> L1-served after first touch.
  const float* xt = x + (size_t)bt * (Jv * Nv) + (size_t)jbase * Nv;
  short8 bfr[2][4];
  #pragma unroll
  for (int jt = 0; jt < 4; ++jt) {
    const float* xp = xt + (size_t)((jt << 4) + m) * Nv + (qd << 3);
    #pragma unroll
    for (int ks = 0; ks < 2; ++ks) {
      float4 a0 = *(const float4*)(xp + (ks << 5));
      float4 a1 = *(const float4*)(xp + (ks << 5) + 4);
      uint4 v;
      v.x = f2bf(a0.x) | (f2bf(a0.y) << 16);
      v.y = f2bf(a0.z) | (f2bf(a0.w) << 16);
      v.z = f2bf(a1.x) | (f2bf(a1.y) << 16);
      v.w = f2bf(a1.z) | (f2bf(a1.w) << 16);
      bfr[ks][jt] = *(short8*)&v;
    }
  }

  // ---- MFMA: acc[lt][jt], D[row=l][col=j]; ks order 0,1 matches prior kernel ----
  floatx4 acc[4][4];
  #pragma unroll
  for (int lt = 0; lt < 4; ++lt)
    #pragma unroll
    for (int jt = 0; jt < 4; ++jt)
      acc[lt][jt] = (floatx4){0.f, 0.f, 0.f, 0.f};

  #pragma unroll
  for (int ks = 0; ks < 2; ++ks)
    #pragma unroll
    for (int jt = 0; jt < 4; ++jt)
      #pragma unroll
      for (int lt = 0; lt < 4; ++lt)
        acc[lt][jt] = __builtin_amdgcn_mfma_f32_16x16x32_bf16(
            afr[ks][lt], bfr[ks][jt], acc[lt][jt], 0, 0, 0);

  // ---- epilogue: per-lane float4 = y[j][l..l+3]; nontemporal (Y never re-read,
  // keeps wt hot in L2). Per instr: 16 rows x 64B contiguous segments. ----
  float* yt = y + (size_t)bt * (Jv * Lv);
  #pragma unroll
  for (int jt = 0; jt < 4; ++jt) {
    float* yr = yt + (size_t)(jbase + (jt << 4) + m) * Lv + lbase + (qd << 2);
    #pragma unroll
    for (int lt = 0; lt < 4; ++lt)
      __builtin_nontemporal_store(acc[lt][jt], (floatx4*)(yr + (lt << 4)));
  }
}

extern "C" void kernel_launch(void* const* d_in, const int* in_sizes, int n_in,
                              void* d_out, int out_size, void* d_ws, size_t ws_size,
                              hipStream_t stream) {
  const float* x    = (const float*)d_in[0];
  const int*   idx  = (const int*)d_in[1];
  const float* w    = (const float*)d_in[2];
  float*       y    = (float*)d_out;

  const size_t wt_bytes = (size_t)INFv * Lv * sizeof(unsigned short);  // 2 MB
  int use_wt = (d_ws != nullptr && ws_size >= wt_bytes) ? 1 : 0;
  unsigned short* wt = (unsigned short*)d_ws;

  if (use_wt) {
    wt_transpose_kernel<<<256, 256, 0, stream>>>(w, wt);
    masklin_kernel<1><<<Bv * Tv * 2, 256, 0, stream>>>(x, idx, wt, w, y);
  } else {
    masklin_kernel<0><<<Bv * Tv * 2, 256, 0, stream>>>(x, idx, (const unsigned short*)nullptr, w, y);
  }
}

// Round 2
// 339.581 us; speedup vs baseline: 1.0607x; 1.0607x over previous
//
#include <hip/hip_runtime.h>
#include <stdint.h>

// Problem constants: B=64, T=32, J=128, N=64, IN_F=4096, OUT_F=256
#define Bv   64
#define Tv   32
#define Jv   128
#define Nv   64
#define Lv   256
#define INFv 4096

typedef __attribute__((ext_vector_type(8))) short  short8;   // 8 bf16 (4 VGPRs) — MFMA A/B frag
typedef __attribute__((ext_vector_type(4))) float  floatx4;  // MFMA C/D frag

// f32 -> bf16 bits, round-to-nearest-even (inputs are finite normals)
__device__ __forceinline__ unsigned int f2bf(float f) {
  union { float f; unsigned int u; } v; v.f = f;
  unsigned int r = v.u + 0x7fffu + ((v.u >> 16) & 1u);
  return r >> 16;
}

// Kernel A (unchanged): transpose+convert full_weight [256][4096] f32 -> Wt [4096][256] bf16.
__global__ __launch_bounds__(256) void wt_transpose_kernel(
    const float* __restrict__ w, unsigned short* __restrict__ wt) {
  int i_base = blockIdx.x * 16;      // 256 blocks x 16 i-values
  int wave = threadIdx.x >> 6;
  int lane = threadIdx.x & 63;
  #pragma unroll
  for (int r = 0; r < 4; ++r) {
    int i = i_base + wave * 4 + r;
    unsigned int b0 = f2bf(w[(size_t)(4 * lane + 0) * INFv + i]);
    unsigned int b1 = f2bf(w[(size_t)(4 * lane + 1) * INFv + i]);
    unsigned int b2 = f2bf(w[(size_t)(4 * lane + 2) * INFv + i]);
    unsigned int b3 = f2bf(w[(size_t)(4 * lane + 3) * INFv + i]);
    uint2 u;
    u.x = b0 | (b1 << 16);
    u.y = b2 | (b3 << 16);
    *(uint2*)(wt + (size_t)i * Lv + 4 * lane) = u;
  }
}

// Main kernel v3: one block per (b,t,j-half). X half-tile staged ONCE to swizzled
// LDS (one barrier, then waves free-run). G gathered register-direct from wt
// (A-operand), X from LDS (B-operand). Per-ks fragment loads keep peak live
// VGPRs ~130 so __launch_bounds__(256,3) (cap 168) holds without spill.
// C/D layout: col=lane&15 -> j, row=qd*4+r -> l => per-lane float4 over l.
template <int USE_WT>
__global__ __launch_bounds__(256, 3) void masklin_kernel(
    const float* __restrict__ x, const int* __restrict__ idx,
    const unsigned short* __restrict__ wt, const float* __restrict__ wfull,
    float* __restrict__ y) {
  __shared__ __align__(16) unsigned short lA[64 * Nv];  // 8 KB: [j'][k] swizzled
  __shared__ int idxs[Nv];

  const int blk  = blockIdx.x;       // 0..4095
  const int bt   = blk >> 1;         // (b,t)
  const int jh   = blk & 1;          // j-half: rows [64*jh, 64*jh+64)
  const int b    = bt >> 5;
  const int t    = bt & 31;
  const int tid  = threadIdx.x;
  const int wave = tid >> 6;
  const int lane = tid & 63;
  const int m    = lane & 15;
  const int qd   = lane >> 4;
  const int lbase = wave << 6;       // wave's l-range [lbase, lbase+64)
  const int jbase = jh << 6;

  // indices[b][n][t], int32 per harness convention
  if (tid < Nv) idxs[tid] = idx[(b * Nv + tid) * Tv + t];

  // ---- stage X half-tile (64x64 f32) -> bf16 swizzled LDS, once per block ----
  // octet O: local row j' = O>>3, chunk c = O&7; element (j',k) at
  // j'*64 + ((k>>3)^(j'&7))*8 + (k&7)  -> all uint4 writes/short8 reads 16B-aligned.
  const float* xt = x + (size_t)bt * (Jv * Nv) + (size_t)jbase * Nv;
  #pragma unroll
  for (int it = 0; it < 2; ++it) {
    int O = tid + it * 256;          // 0..511
    int j = O >> 3, c = O & 7;
    const float4* p = (const float4*)(xt + (size_t)O * 8);
    float4 a0 = p[0], a1 = p[1];
    uint4 v;
    v.x = f2bf(a0.x) | (f2bf(a0.y) << 16);
    v.y = f2bf(a0.z) | (f2bf(a0.w) << 16);
    v.z = f2bf(a1.x) | (f2bf(a1.y) << 16);
    v.w = f2bf(a1.z) | (f2bf(a1.w) << 16);
    *(uint4*)&lA[j * 64 + ((c ^ (j & 7)) << 3)] = v;
  }
  __syncthreads();                   // lA + idxs visible; no further barriers

  floatx4 acc[4][4];
  #pragma unroll
  for (int lt = 0; lt < 4; ++lt)
    #pragma unroll
    for (int jt = 0; jt < 4; ++jt)
      acc[lt][jt] = (floatx4){0.f, 0.f, 0.f, 0.f};

  #pragma unroll
  for (int ks = 0; ks < 2; ++ks) {
    // ---- rows this lane needs: n = ks*32 + qd*8 + j (8 values, from LDS) ----
    int rows[8];
    #pragma unroll
    for (int j = 0; j < 8; ++j)
      rows[j] = idxs[(ks << 5) + (qd << 3) + j];

    // ---- A fragments: afr[lt] elem j = wt[rows[j]][lcol] (register-direct) ----
    // Per instr: 4 qd-rows x 32B contiguous — wt is L2-resident (2 MB).
    short8 afr[4];
    #pragma unroll
    for (int lt = 0; lt < 4; ++lt) {
      const int lcol = lbase + (lt << 4) + m;
      unsigned int e[8];
      #pragma unroll
      for (int j = 0; j < 8; ++j) {
        if (USE_WT) {
          e[j] = wt[(unsigned int)rows[j] * Lv + lcol];
        } else {
          e[j] = f2bf(wfull[(size_t)lcol * INFv + rows[j]]);  // fallback, slow
        }
      }
      uint4 v;
      v.x = e[0] | (e[1] << 16);
      v.y = e[2] | (e[3] << 16);
      v.z = e[4] | (e[5] << 16);
      v.w = e[6] | (e[7] << 16);
      afr[lt] = *(short8*)&v;
    }

    // ---- B fragments from swizzled LDS: 8 consecutive k at chunk=ks*4+qd ----
    const int chunk = (ks << 2) + qd;
    short8 bfr[4];
    #pragma unroll
    for (int jt = 0; jt < 4; ++jt) {
      int j = (jt << 4) + m;
      bfr[jt] = *(const short8*)&lA[j * 64 + ((chunk ^ (j & 7)) << 3)];
    }

    // ---- MFMA: D[row=l][col=j] ----
    #pragma unroll
    for (int jt = 0; jt < 4; ++jt)
      #pragma unroll
      for (int lt = 0; lt < 4; ++lt)
        acc[lt][jt] = __builtin_amdgcn_mfma_f32_16x16x32_bf16(
            afr[lt], bfr[jt], acc[lt][jt], 0, 0, 0);
  }

  // ---- epilogue: per-lane float4 = y[j][l..l+3]; nontemporal (Y never re-read,
  // keeps wt hot in L2). Per instr: 16 rows x 4 x 16B = 64B segments. ----
  float* yt = y + (size_t)bt * (Jv * Lv);
  #pragma unroll
  for (int jt = 0; jt < 4; ++jt) {
    float* yr = yt + (size_t)(jbase + (jt << 4) + m) * Lv + lbase + (qd << 2);
    #pragma unroll
    for (int lt = 0; lt < 4; ++lt)
      __builtin_nontemporal_store(acc[lt][jt], (floatx4*)(yr + (lt << 4)));
  }
}

extern "C" void kernel_launch(void* const* d_in, const int* in_sizes, int n_in,
                              void* d_out, int out_size, void* d_ws, size_t ws_size,
                              hipStream_t stream) {
  const float* x    = (const float*)d_in[0];
  const int*   idx  = (const int*)d_in[1];
  const float* w    = (const float*)d_in[2];
  float*       y    = (float*)d_out;

  const size_t wt_bytes = (size_t)INFv * Lv * sizeof(unsigned short);  // 2 MB
  int use_wt = (d_ws != nullptr && ws_size >= wt_bytes) ? 1 : 0;
  unsigned short* wt = (unsigned short*)d_ws;

  if (use_wt) {
    wt_transpose_kernel<<<256, 256, 0, stream>>>(w, wt);
    masklin_kernel<1><<<Bv * Tv * 2, 256, 0, stream>>>(x, idx, wt, w, y);
  } else {
    masklin_kernel<0><<<Bv * Tv * 2, 256, 0, stream>>>(x, idx, (const unsigned short*)nullptr, w, y);
  }
}

// Round 4
// 329.319 us; speedup vs baseline: 1.0937x; 1.0312x over previous
//
#include <hip/hip_runtime.h>
#include <stdint.h>

// Problem constants: B=64, T=32, J=128, N=64, IN_F=4096, OUT_F=256
#define Bv   64
#define Tv   32
#define Jv   128
#define Nv   64
#define Lv   256
#define INFv 4096

typedef __attribute__((ext_vector_type(8))) short  short8;   // 8 bf16 (4 VGPRs) — MFMA A/B frag
typedef __attribute__((ext_vector_type(4))) float  floatx4;  // MFMA C/D frag

// f32 -> bf16 bits, round-to-nearest-even (inputs are finite normals)
__device__ __forceinline__ unsigned int f2bf(float f) {
  union { float f; unsigned int u; } v; v.f = f;
  unsigned int r = v.u + 0x7fffu + ((v.u >> 16) & 1u);
  return r >> 16;
}

// Kernel A (unchanged): transpose+convert full_weight [256][4096] f32 -> Wt [4096][256] bf16.
__global__ __launch_bounds__(256) void wt_transpose_kernel(
    const float* __restrict__ w, unsigned short* __restrict__ wt) {
  int i_base = blockIdx.x * 16;      // 256 blocks x 16 i-values
  int wave = threadIdx.x >> 6;
  int lane = threadIdx.x & 63;
  #pragma unroll
  for (int r = 0; r < 4; ++r) {
    int i = i_base + wave * 4 + r;
    unsigned int b0 = f2bf(w[(size_t)(4 * lane + 0) * INFv + i]);
    unsigned int b1 = f2bf(w[(size_t)(4 * lane + 1) * INFv + i]);
    unsigned int b2 = f2bf(w[(size_t)(4 * lane + 2) * INFv + i]);
    unsigned int b3 = f2bf(w[(size_t)(4 * lane + 3) * INFv + i]);
    uint2 u;
    u.x = b0 | (b1 << 16);
    u.y = b2 | (b3 << 16);
    *(uint2*)(wt + (size_t)i * Lv + 4 * lane) = u;
  }
}

// Main kernel v4: one block per (b,t), grid 2048. Stage BOTH j-halves of X
// up-front (32 KB LDS, ONE barrier), then compute+store half0, half1
// sequentially: half0's store drain overlaps half1's gather+MFMA (no barrier
// between). G = wt[idx[n]][l] is j-independent -> half1's register gather
// re-reads the same lines L1-hot. Plain (cached) float4 stores so L2 merges
// the 64B half-line segments.
// C/D layout: col=lane&15 -> j, row=qd*4+r -> l => per-lane float4 over l.
template <int USE_WT>
__global__ __launch_bounds__(256, 3) void masklin_kernel(
    const float* __restrict__ x, const int* __restrict__ idx,
    const unsigned short* __restrict__ wt, const float* __restrict__ wfull,
    float* __restrict__ y) {
  __shared__ __align__(16) unsigned short lA[2][64 * Nv];  // 2 x 8 KB, [j'][k] swizzled
  __shared__ int idxs[Nv];

  const int bt   = blockIdx.x;       // 0..2047
  const int b    = bt >> 5;
  const int t    = bt & 31;
  const int tid  = threadIdx.x;
  const int wave = tid >> 6;
  const int lane = tid & 63;
  const int m    = lane & 15;
  const int qd   = lane >> 4;
  const int lbase = wave << 6;       // wave's l-range [lbase, lbase+64)

  // indices[b][n][t], int32 per harness convention (loaded ONCE per bt)
  if (tid < Nv) idxs[tid] = idx[(b * Nv + tid) * Tv + t];

  // ---- stage full X tile (128x64 f32, contiguous) -> bf16 swizzled LDS ----
  // octet O (0..1023): half = O>>9, local row j' = (O>>3)&63, chunk c = O&7;
  // element (j',k) at lA[half][j'*64 + ((k>>3)^(j'&7))*8 + (k&7)] -> 16B aligned.
  const float* xt = x + (size_t)bt * (Jv * Nv);
  #pragma unroll
  for (int it = 0; it < 4; ++it) {
    int O = tid + it * 256;          // 0..1023
    int hf = O >> 9, j = (O >> 3) & 63, c = O & 7;
    const float4* p = (const float4*)(xt + (size_t)O * 8);
    float4 a0 = p[0], a1 = p[1];
    uint4 v;
    v.x = f2bf(a0.x) | (f2bf(a0.y) << 16);
    v.y = f2bf(a0.z) | (f2bf(a0.w) << 16);
    v.z = f2bf(a1.x) | (f2bf(a1.y) << 16);
    v.w = f2bf(a1.z) | (f2bf(a1.w) << 16);
    *(uint4*)&lA[hf][j * 64 + ((c ^ (j & 7)) << 3)] = v;
  }
  __syncthreads();                   // the ONLY barrier

  float* yt = y + (size_t)bt * (Jv * Lv);

  #pragma unroll 1                   // keep halves sequential: acc stays 64 VGPR,
  for (int hf = 0; hf < 2; ++hf) {   // half0 stores drain under half1 compute
    const int jbase = hf << 6;

    floatx4 acc[4][4];
    #pragma unroll
    for (int lt = 0; lt < 4; ++lt)
      #pragma unroll
      for (int jt = 0; jt < 4; ++jt)
        acc[lt][jt] = (floatx4){0.f, 0.f, 0.f, 0.f};

    #pragma unroll
    for (int ks = 0; ks < 2; ++ks) {
      // rows this lane needs: n = ks*32 + qd*8 + j (8 values)
      int rows[8];
      #pragma unroll
      for (int j = 0; j < 8; ++j)
        rows[j] = idxs[(ks << 5) + (qd << 3) + j];

      // A fragments: afr[lt] elem j = wt[rows[j]][lcol] (register-direct).
      // Per instr: 4 qd-rows x 32B segments; L2-resident, L1-hot on hf=1.
      short8 afr[4];
      #pragma unroll
      for (int lt = 0; lt < 4; ++lt) {
        const int lcol = lbase + (lt << 4) + m;
        unsigned int e[8];
        #pragma unroll
        for (int j = 0; j < 8; ++j) {
          if (USE_WT) {
            e[j] = wt[((unsigned int)rows[j] << 8) + lcol];
          } else {
            e[j] = f2bf(wfull[(size_t)lcol * INFv + rows[j]]);  // fallback, slow
          }
        }
        uint4 v;
        v.x = e[0] | (e[1] << 16);
        v.y = e[2] | (e[3] << 16);
        v.z = e[4] | (e[5] << 16);
        v.w = e[6] | (e[7] << 16);
        afr[lt] = *(short8*)&v;
      }

      // B fragments from swizzled LDS: 8 consecutive k at chunk = ks*4+qd
      const int chunk = (ks << 2) + qd;
      short8 bfr[4];
      #pragma unroll
      for (int jt = 0; jt < 4; ++jt) {
        int j = (jt << 4) + m;
        bfr[jt] = *(const short8*)&lA[hf][j * 64 + ((chunk ^ (j & 7)) << 3)];
      }

      // MFMA: D[row=l][col=j]
      #pragma unroll
      for (int jt = 0; jt < 4; ++jt)
        #pragma unroll
        for (int lt = 0; lt < 4; ++lt)
          acc[lt][jt] = __builtin_amdgcn_mfma_f32_16x16x32_bf16(
              afr[lt], bfr[jt], acc[lt][jt], 0, 0, 0);
    }

    // epilogue: per-lane float4 = y[j][l..l+3], PLAIN stores (L2 write-back
    // merges the 64B half-lines). Per instr: 16 rows x 64B segments.
    #pragma unroll
    for (int jt = 0; jt < 4; ++jt) {
      float* yr = yt + (size_t)(jbase + (jt << 4) + m) * Lv + lbase + (qd << 2);
      #pragma unroll
      for (int lt = 0; lt < 4; ++lt)
        *(floatx4*)(yr + (lt << 4)) = acc[lt][jt];
    }
  }
}

extern "C" void kernel_launch(void* const* d_in, const int* in_sizes, int n_in,
                              void* d_out, int out_size, void* d_ws, size_t ws_size,
                              hipStream_t stream) {
  const float* x    = (const float*)d_in[0];
  const int*   idx  = (const int*)d_in[1];
  const float* w    = (const float*)d_in[2];
  float*       y    = (float*)d_out;

  const size_t wt_bytes = (size_t)INFv * Lv * sizeof(unsigned short);  // 2 MB
  int use_wt = (d_ws != nullptr && ws_size >= wt_bytes) ? 1 : 0;
  unsigned short* wt = (unsigned short*)d_ws;

  if (use_wt) {
    wt_transpose_kernel<<<256, 256, 0, stream>>>(w, wt);
    masklin_kernel<1><<<Bv * Tv, 256, 0, stream>>>(x, idx, wt, w, y);
  } else {
    masklin_kernel<0><<<Bv * Tv, 256, 0, stream>>>(x, idx, (const unsigned short*)nullptr, w, y);
  }
}

// Round 6
// 327.712 us; speedup vs baseline: 1.0991x; 1.0049x over previous
//
#include <hip/hip_runtime.h>
#include <stdint.h>

// Problem constants: B=64, T=32, J=128, N=64, IN_F=4096, OUT_F=256
#define Bv   64
#define Tv   32
#define Jv   128
#define Nv   64
#define Lv   256
#define INFv 4096

typedef __attribute__((ext_vector_type(8))) short  short8;   // 8 bf16 (4 VGPRs) — MFMA A/B frag
typedef __attribute__((ext_vector_type(4))) float  floatx4;  // MFMA C/D frag

// f32 -> bf16 bits, round-to-nearest-even (inputs are finite normals)
__device__ __forceinline__ unsigned int f2bf(float f) {
  union { float f; unsigned int u; } v; v.f = f;
  unsigned int r = v.u + 0x7fffu + ((v.u >> 16) & 1u);
  return r >> 16;
}

// Kernel A (unchanged): transpose+convert full_weight [256][4096] f32 -> Wt [4096][256] bf16.
__global__ __launch_bounds__(256) void wt_transpose_kernel(
    const float* __restrict__ w, unsigned short* __restrict__ wt) {
  int i_base = blockIdx.x * 16;      // 256 blocks x 16 i-values
  int wave = threadIdx.x >> 6;
  int lane = threadIdx.x & 63;
  #pragma unroll
  for (int r = 0; r < 4; ++r) {
    int i = i_base + wave * 4 + r;
    unsigned int b0 = f2bf(w[(size_t)(4 * lane + 0) * INFv + i]);
    unsigned int b1 = f2bf(w[(size_t)(4 * lane + 1) * INFv + i]);
    unsigned int b2 = f2bf(w[(size_t)(4 * lane + 2) * INFv + i]);
    unsigned int b3 = f2bf(w[(size_t)(4 * lane + 3) * INFv + i]);
    uint2 u;
    u.x = b0 | (b1 << 16);
    u.y = b2 | (b3 << 16);
    *(uint2*)(wt + (size_t)i * Lv + 4 * lane) = u;
  }
}

// Main kernel v5: v4 structure (one block per (b,t), both halves staged once,
// single barrier, register-direct wt gather) + NEW epilogue: wave-private LDS
// transpose so every global store instruction writes 4 rows x 256B contiguous
// segments (full 128B lines) instead of 16 x 64B partial-line segments.
// Tests the Y-write-amplification theory for the ~100us window deficit.
// C/D layout: col=lane&15 -> j, row=qd*4+r -> l.
template <int USE_WT>
__global__ __launch_bounds__(256, 3) void masklin_kernel(
    const float* __restrict__ x, const int* __restrict__ idx,
    const unsigned short* __restrict__ wt, const float* __restrict__ wfull,
    float* __restrict__ y) {
  __shared__ __align__(16) unsigned short lA[2][64 * Nv];  // 2 x 8 KB, [j'][k] swizzled
  __shared__ __align__(16) float sOut[4][1024];            // 16 KB: 4 KB/wave store-staging
  __shared__ int idxs[Nv];

  const int bt   = blockIdx.x;       // 0..2047
  const int b    = bt >> 5;
  const int t    = bt & 31;
  const int tid  = threadIdx.x;
  const int wave = tid >> 6;
  const int lane = tid & 63;
  const int m    = lane & 15;
  const int qd   = lane >> 4;
  const int lbase = wave << 6;       // wave's l-range [lbase, lbase+64)

  // indices[b][n][t], int32 per harness convention (loaded ONCE per bt)
  if (tid < Nv) idxs[tid] = idx[(b * Nv + tid) * Tv + t];

  // ---- stage full X tile (128x64 f32, contiguous) -> bf16 swizzled LDS ----
  // octet O (0..1023): half = O>>9, local row j' = (O>>3)&63, chunk c = O&7;
  // element (j',k) at lA[half][j'*64 + ((k>>3)^(j'&7))*8 + (k&7)] -> 16B aligned.
  const float* xt = x + (size_t)bt * (Jv * Nv);
  #pragma unroll
  for (int it = 0; it < 4; ++it) {
    int O = tid + it * 256;          // 0..1023
    int hf = O >> 9, j = (O >> 3) & 63, c = O & 7;
    const float4* p = (const float4*)(xt + (size_t)O * 8);
    float4 a0 = p[0], a1 = p[1];
    uint4 v;
    v.x = f2bf(a0.x) | (f2bf(a0.y) << 16);
    v.y = f2bf(a0.z) | (f2bf(a0.w) << 16);
    v.z = f2bf(a1.x) | (f2bf(a1.y) << 16);
    v.w = f2bf(a1.z) | (f2bf(a1.w) << 16);
    *(uint4*)&lA[hf][j * 64 + ((c ^ (j & 7)) << 3)] = v;
  }
  __syncthreads();                   // the ONLY barrier

  float* yt = y + (size_t)bt * (Jv * Lv);
  float* sw = &sOut[wave][0];        // wave-private: no barriers needed

  #pragma unroll 1                   // keep halves sequential: acc stays 64 VGPR,
  for (int hf = 0; hf < 2; ++hf) {   // half0 stores drain under half1 compute
    const int jbase = hf << 6;

    floatx4 acc[4][4];
    #pragma unroll
    for (int lt = 0; lt < 4; ++lt)
      #pragma unroll
      for (int jt = 0; jt < 4; ++jt)
        acc[lt][jt] = (floatx4){0.f, 0.f, 0.f, 0.f};

    #pragma unroll
    for (int ks = 0; ks < 2; ++ks) {
      // rows this lane needs: n = ks*32 + qd*8 + j (8 values)
      int rows[8];
      #pragma unroll
      for (int j = 0; j < 8; ++j)
        rows[j] = idxs[(ks << 5) + (qd << 3) + j];

      // A fragments: afr[lt] elem j = wt[rows[j]][lcol] (register-direct).
      // Per instr: 4 qd-rows x 32B segments; L2-resident, L1-hot on hf=1.
      short8 afr[4];
      #pragma unroll
      for (int lt = 0; lt < 4; ++lt) {
        const int lcol = lbase + (lt << 4) + m;
        unsigned int e[8];
        #pragma unroll
        for (int j = 0; j < 8; ++j) {
          if (USE_WT) {
            e[j] = wt[((unsigned int)rows[j] << 8) + lcol];
          } else {
            e[j] = f2bf(wfull[(size_t)lcol * INFv + rows[j]]);  // fallback, slow
          }
        }
        uint4 v;
        v.x = e[0] | (e[1] << 16);
        v.y = e[2] | (e[3] << 16);
        v.z = e[4] | (e[5] << 16);
        v.w = e[6] | (e[7] << 16);
        afr[lt] = *(short8*)&v;
      }

      // B fragments from swizzled LDS: 8 consecutive k at chunk = ks*4+qd
      const int chunk = (ks << 2) + qd;
      short8 bfr[4];
      #pragma unroll
      for (int jt = 0; jt < 4; ++jt) {
        int j = (jt << 4) + m;
        bfr[jt] = *(const short8*)&lA[hf][j * 64 + ((chunk ^ (j & 7)) << 3)];
      }

      // MFMA: D[row=l][col=j]
      #pragma unroll
      for (int jt = 0; jt < 4; ++jt)
        #pragma unroll
        for (int lt = 0; lt < 4; ++lt)
          acc[lt][jt] = __builtin_amdgcn_mfma_f32_16x16x32_bf16(
              afr[lt], bfr[jt], acc[lt][jt], 0, 0, 0);
    }

    // ---- epilogue v5: per-jt wave-private LDS transpose ----
    // Logical tile per jt: rows j' = 0..15 (j = jbase+jt*16+j'), cols 0..63
    // (l = lbase+col). Chunk = 4 floats; logical chunk L at row R stored at
    // physical chunk L^R (bijective per row; writes 2-way bank = free).
    // Same-wave DS ops execute in order -> jt reuse of sw is safe, no barrier.
    #pragma unroll
    for (int jt = 0; jt < 4; ++jt) {
      // scatter: lane(qd,m) holds acc[lt][jt] = y-row m, cols lt*16+qd*4+0..3
      // -> row m, logical chunk c = lt*4+qd
      #pragma unroll
      for (int lt = 0; lt < 4; ++lt) {
        int c = (lt << 2) + qd;
        *(floatx4*)&sw[(m << 6) + ((c ^ m) << 2)] = acc[lt][jt];
      }
      // gather: lane(qd,m), pass p: row jr = p*4+qd, logical chunk m
      // -> store float4 to y[jbase+jt*16+jr][lbase+m*4 .. +3]
      // Per instr: 4 rows x (16 lanes x 16B = 256B contiguous) = full lines.
      #pragma unroll
      for (int p = 0; p < 4; ++p) {
        int jr = (p << 2) + qd;
        floatx4 v = *(const floatx4*)&sw[(jr << 6) + ((m ^ jr) << 2)];
        *(floatx4*)(yt + (size_t)(jbase + (jt << 4) + jr) * Lv + lbase + (m << 2)) = v;
      }
    }
  }
}

extern "C" void kernel_launch(void* const* d_in, const int* in_sizes, int n_in,
                              void* d_out, int out_size, void* d_ws, size_t ws_size,
                              hipStream_t stream) {
  const float* x    = (const float*)d_in[0];
  const int*   idx  = (const int*)d_in[1];
  const float* w    = (const float*)d_in[2];
  float*       y    = (float*)d_out;

  const size_t wt_bytes = (size_t)INFv * Lv * sizeof(unsigned short);  // 2 MB
  int use_wt = (d_ws != nullptr && ws_size >= wt_bytes) ? 1 : 0;
  unsigned short* wt = (unsigned short*)d_ws;

  if (use_wt) {
    wt_transpose_kernel<<<256, 256, 0, stream>>>(w, wt);
    masklin_kernel<1><<<Bv * Tv, 256, 0, stream>>>(x, idx, wt, w, y);
  } else {
    masklin_kernel<0><<<Bv * Tv, 256, 0, stream>>>(x, idx, (const unsigned short*)nullptr, w, y);
  }
}